// Round 14
// baseline (253.376 us; speedup 1.0000x reference)
//
#include <hip/hip_runtime.h>

typedef unsigned short USH;
typedef short s16x8 __attribute__((ext_vector_type(8)));
typedef float f32x4 __attribute__((ext_vector_type(4)));
typedef float f32x4v __attribute__((ext_vector_type(4)));
typedef unsigned int u32x4 __attribute__((ext_vector_type(4)));
// may_alias variants for ALL type-punned LDS/global accesses.
typedef s16x8 s16x8_a __attribute__((may_alias));
typedef f32x4v f32x4v_a __attribute__((may_alias));
typedef u32x4 u32x4_a __attribute__((may_alias));
typedef unsigned long long u64_a __attribute__((may_alias));

#if __has_builtin(__builtin_amdgcn_exp2f)
#define EXP2F(x) __builtin_amdgcn_exp2f(x)  // raw v_exp_f32, no legalization
#else
#define EXP2F(x) __builtin_exp2f(x)
#endif

__device__ __forceinline__ USH f2bf(float f) {
  union { float f; unsigned int i; } c; c.f = f;
  unsigned int x = c.i;
  return (USH)((x + 0x7FFFu + ((x >> 16) & 1u)) >> 16);
}
__device__ __forceinline__ unsigned int pk_bf16(float a, float b) {
#if __has_builtin(__builtin_amdgcn_cvt_pk_bf16_f32)
  typedef USH ush2 __attribute__((ext_vector_type(2)));
  union { ush2 v; unsigned int u; } r;
  r.v = __builtin_amdgcn_cvt_pk_bf16_f32(a, b);
  return r.u;
#else
  union { float f; unsigned int i; } ca, cb; ca.f = a; cb.f = b;
  return ((ca.i + 0x8000u) >> 16) | ((cb.i + 0x8000u) & 0xFFFF0000u);
#endif
}

__device__ __forceinline__ f32x4 mfma16(s16x8 a, s16x8 b, f32x4 c) {
  return __builtin_amdgcn_mfma_f32_16x16x32_bf16(a, b, c, 0, 0, 0);
}

// async global->LDS, 16B per lane; LDS dest semantics: wave base + lane*16.
#if __has_builtin(__builtin_amdgcn_global_load_lds)
__device__ __forceinline__ void gld_lds16(const USH* g, USH* l) {
  __builtin_amdgcn_global_load_lds(
      static_cast<const unsigned int __attribute__((address_space(1)))*>(
          (const void __attribute__((address_space(1)))*)g),
      static_cast<unsigned int __attribute__((address_space(3)))*>(
          (void __attribute__((address_space(3)))*)l),
      16, 0, 0);
}
#else
__device__ __forceinline__ void gld_lds16(const USH* g, USH* l) {
  *(s16x8_a*)l = *(const s16x8_a*)g;  // fallback: synchronous copy, same addresses
}
#endif

// ------------- weight transpose + fp32->bf16: WT[n][k] = bf16(W[k][n]) -------------
__global__ void transpose_w(const float* __restrict__ Wq, const float* __restrict__ Wk,
                            const float* __restrict__ Wv, const float* __restrict__ Wo,
                            USH* __restrict__ wsT) {
  __shared__ float tile[32][33];
  const int z = blockIdx.z;
  const float* W = (z == 0) ? Wq : (z == 1) ? Wk : (z == 2) ? Wv : Wo;
  USH* WT = wsT + (size_t)z * 262144;
  const int n0 = blockIdx.x * 32, k0 = blockIdx.y * 32;
  const int tx = threadIdx.x, ty = threadIdx.y;  // 32 x 8
  #pragma unroll
  for (int i = 0; i < 4; ++i)
    tile[ty + i * 8][tx] = W[(size_t)(k0 + ty + i * 8) * 512 + n0 + tx];
  __syncthreads();
  #pragma unroll
  for (int i = 0; i < 4; ++i)
    WT[(size_t)(n0 + ty + i * 8) * 512 + k0 + tx] = f2bf(tile[tx][ty + i * 8]);
}

// ---------------- x fp32 -> bf16 (one-shot, so GEMM stages bf16 A) ----------------
__global__ __launch_bounds__(256) void cvt_x(const float* __restrict__ x,
                                             USH* __restrict__ xb) {
  const size_t i = ((size_t)blockIdx.x * 256 + threadIdx.x) * 8;
  const f32x4v a = *(const f32x4v_a*)(x + i);
  const f32x4v b = *(const f32x4v_a*)(x + i + 4);
  u32x4 s;
  s.x = pk_bf16(a.x, a.y); s.y = pk_bf16(a.z, a.w);
  s.z = pk_bf16(b.x, b.y); s.w = pk_bf16(b.z, b.w);
  *(u32x4_a*)(xb + i) = s;
}

// ---------------- GEMM: out = A[M,512](bf16) * WT^T + bias ----------------
// MODE 0: float out[m*512+n] (d_out fp32).
// MODE 1: z==0 -> Q bf16 [B,H,S,Hd] scaled by sc*log2e; z==1 -> K [B,H,S,Hd];
//         z==2 -> V [B,H,Hd,S] (pre-transposed for attn).
// Operand-swap epilogue: for MODE 0 and z<2 we compute mfma(B,A) so D-rows =
// n-dim -> each lane's 4 r-values are 4 CONSECUTIVE output elements ->
// float4 / packed-b64 stores (16 stores/lane instead of 64 scalar).
// z==2 keeps normal orientation (rows = s, also consecutive for its layout).
template <int MODE>
__global__ __launch_bounds__(256, 3) void gemm_bias(
    const USH* __restrict__ A, const USH* __restrict__ BT0,
    const float* __restrict__ b0, const float* __restrict__ b1,
    const float* __restrict__ b2,
    USH* __restrict__ oQ, USH* __restrict__ oKV, float* __restrict__ oF) {
  __shared__ __align__(16) USH As[128 * 68];
  __shared__ __align__(16) USH Bs[128 * 68];
  const int z = blockIdx.z;
  const USH* BT = BT0 + (size_t)z * 262144;
  const float* bias = (z == 0) ? b0 : ((z == 1) ? b1 : b2);
  USH* outb = (z == 0) ? oQ : (oKV + (size_t)(z - 1) * 4194304);
  const float qs = (MODE == 1 && z == 0) ? 0.06375871528132839f : 1.0f;
  const bool swp = (MODE == 0) || (z < 2);

  const int t = threadIdx.x;
  const int w = t >> 6, lane = t & 63;
  const int c = lane & 15, g = lane >> 4;
  const int wm = w & 1, wn = w >> 1;
  const int m0 = blockIdx.x * 128, n0 = blockIdx.y * 128;
  const int srow = t >> 1, scol = (t & 1) * 32;

  f32x4 acc[4][4] = {};  // swp: [nf][mf]; else [mf][nf]

  const USH* Ap0 = A + (size_t)(m0 + srow) * 512 + scol;
  const USH* Bp0 = BT + (size_t)(n0 + srow) * 512 + scol;
  s16x8 pa[4], pb[4];
  #pragma unroll
  for (int j = 0; j < 4; ++j) {
    pa[j] = *(const s16x8_a*)(Ap0 + j * 8);
    pb[j] = *(const s16x8_a*)(Bp0 + j * 8);
  }

  for (int kt = 0; kt < 8; ++kt) {
    __syncthreads();
    #pragma unroll
    for (int j = 0; j < 4; ++j) {
      *(s16x8_a*)(As + srow * 68 + scol + j * 8) = pa[j];
      *(s16x8_a*)(Bs + srow * 68 + scol + j * 8) = pb[j];
    }
    const int ktn = (kt < 7) ? kt + 1 : kt;
    #pragma unroll
    for (int j = 0; j < 4; ++j) {
      pa[j] = *(const s16x8_a*)(Ap0 + ktn * 64 + j * 8);
      pb[j] = *(const s16x8_a*)(Bp0 + ktn * 64 + j * 8);
    }
    __syncthreads();
    #pragma unroll
    for (int ks = 0; ks < 2; ++ks) {
      s16x8 af[4], bfr[4];
      #pragma unroll
      for (int i = 0; i < 4; ++i) {
        af[i]  = *(const s16x8_a*)(As + (wm * 64 + i * 16 + c) * 68 + ks * 32 + g * 8);
        bfr[i] = *(const s16x8_a*)(Bs + (wn * 64 + i * 16 + c) * 68 + ks * 32 + g * 8);
      }
      if (swp) {
        #pragma unroll
        for (int nf = 0; nf < 4; ++nf)
          #pragma unroll
          for (int mf = 0; mf < 4; ++mf)
            acc[nf][mf] = mfma16(bfr[nf], af[mf], acc[nf][mf]);
      } else {
        #pragma unroll
        for (int mf = 0; mf < 4; ++mf)
          #pragma unroll
          for (int nf = 0; nf < 4; ++nf)
            acc[mf][nf] = mfma16(af[mf], bfr[nf], acc[mf][nf]);
      }
    }
  }

  if (MODE == 0) {
    // swp: lane: m = m0+wm*64+mf*16+c (col), n = n0+wn*64+nf*16+g*4+r (row)
    #pragma unroll
    for (int nf = 0; nf < 4; ++nf) {
      const int nb = n0 + wn * 64 + nf * 16 + g * 4;
      const f32x4v bv4 = *(const f32x4v_a*)(bias + nb);
      #pragma unroll
      for (int mf = 0; mf < 4; ++mf) {
        const int m = m0 + wm * 64 + mf * 16 + c;
        f32x4v v;
        #pragma unroll
        for (int r = 0; r < 4; ++r) v[r] = acc[nf][mf][r] + bv4[r];
        *(f32x4v_a*)(oF + (size_t)m * 512 + nb) = v;
      }
    }
  } else if (z < 2) {
    #pragma unroll
    for (int nf = 0; nf < 4; ++nf) {
      const int nb = n0 + wn * 64 + nf * 16 + g * 4;
      const int h = nb >> 6, hd0 = nb & 63;
      const f32x4v bv4 = *(const f32x4v_a*)(bias + nb);
      #pragma unroll
      for (int mf = 0; mf < 4; ++mf) {
        const int m = m0 + wm * 64 + mf * 16 + c;
        const int bb = m >> 12, s = m & 4095;
        const unsigned int lo = pk_bf16((acc[nf][mf][0] + bv4[0]) * qs,
                                        (acc[nf][mf][1] + bv4[1]) * qs);
        const unsigned int hi = pk_bf16((acc[nf][mf][2] + bv4[2]) * qs,
                                        (acc[nf][mf][3] + bv4[3]) * qs);
        *(u64_a*)(outb + ((size_t)(bb * 8 + h) * 4096 + s) * 64 + hd0) =
            (unsigned long long)lo | ((unsigned long long)hi << 32);
      }
    }
  } else {
    // z==2 normal: n = n0+wn*64+nf*16+c (col), s = m0+wm*64+mf*16+g*4+r (row)
    #pragma unroll
    for (int nf = 0; nf < 4; ++nf) {
      const int n = n0 + wn * 64 + nf * 16 + c;
      const int h = n >> 6, hd = n & 63;
      const float bv = bias[n];
      #pragma unroll
      for (int mf = 0; mf < 4; ++mf) {
        const int mb = m0 + wm * 64 + mf * 16 + g * 4;
        const int bb = mb >> 12, s0 = mb & 4095;
        const unsigned int lo = pk_bf16(acc[mf][nf][0] + bv, acc[mf][nf][1] + bv);
        const unsigned int hi = pk_bf16(acc[mf][nf][2] + bv, acc[mf][nf][3] + bv);
        *(u64_a*)(outb + ((size_t)(bb * 8 + h) * 64 + hd) * 4096 + s0) =
            (unsigned long long)lo | ((unsigned long long)hi << 32);
      }
    }
  }
}

// ---------------- flash attention v9: 8-wave blocks + async-DMA dbuf ----------------
// grid: (32 q-tiles, 16 bh). block 512 = 8 waves, each wave owns 16 q-rows ->
// 16 waves/CU (2 blocks) for 2x the pipe-overlap concurrency of the 4-wave version.
// K/V staged via global_load_lds into XOR-swizzled LDS (read layouts byte-identical
// to the round-13 conflict-free ones; staging lane-maps re-derived for 8 waves):
//   K [half][key][64B]: phys chunk q holds global chunk q ^ ((key>>1)&3)
//   V [hd][128B]:       phys chunk q holds global chunk q ^ (hd&7)
// Double-buffered, one barrier/iter; DMA for kt+1 flies across the full iteration.
// Q pre-scaled by sc*log2e -> p = exp2(s). l = P.1 on the MFMA pipe.
__global__ __launch_bounds__(512, 4) void attn(const USH* __restrict__ Qbuf,
                                               const USH* __restrict__ kv,
                                               USH* __restrict__ att) {
  __shared__ __align__(16) USH Ks[2 * 4096];   // [buf][half*64+key][32 USH]
  __shared__ __align__(16) USH Vt[2 * 4096];   // [buf][64 hd][64 USH]
  __shared__ __align__(16) USH Ps[8][16 * 76]; // per-wave [16 qrow][76 key-pad]
  __shared__ float lbuf[8][16];

  const int t = threadIdx.x;
  const int w = t >> 6, lane = t & 63;
  const int c = lane & 15, g = lane >> 4;
  const int bh = blockIdx.y;
  const int bb = bh >> 3, hh = bh & 7;
  const size_t base = (size_t)bh * 262144;  // 4096*64
  const USH* Q = Qbuf + base;
  const USH* K = kv + base;                 // [S,Hd]
  const USH* V = kv + 4194304 + base;       // [Hd,S] (pre-transposed)
  const int q0 = blockIdx.x * 128 + w * 16;

  // Q fragments (B-operand of S^T): registers for the whole K loop
  s16x8 qf[2];
  #pragma unroll
  for (int kh = 0; kh < 2; ++kh)
    qf[kh] = *(const s16x8_a*)(Q + (size_t)(q0 + c) * 64 + kh * 32 + g * 8);

  // constant ones-column B-fragment: l = P . 1 on the MFMA pipe
  s16x8 onesf;
  {
    const short one = (short)0x3F80, val = (c == 0) ? one : (short)0;
    #pragma unroll
    for (int j = 0; j < 8; ++j) onesf[j] = val;
  }

  f32x4 o[4] = {};
  f32x4 o_l = {};

  // --- DMA lane mappings ---
  // K: wave w stages phys rows p in [w*16, w*16+16); p = half*64+key.
  const int pK = w * 16 + (lane >> 2);
  const int keyK = pK & 63, halfK = pK >> 6;
  const int ccK = (lane & 3) ^ ((keyK >> 1) & 3);
  const USH* gK0 = K + (size_t)keyK * 64 + halfK * 32 + ccK * 8;  // +kt*4096
  // V: wave w stages hd in [w*8, w*8+8)
  const int hdV = w * 8 + (lane >> 3);
  const int ccV = (lane & 7) ^ (hdV & 7);
  const USH* gV0 = V + (size_t)hdV * 4096 + ccV * 8;              // +kt*64
  USH* lK = Ks + w * 512 + lane * 8;   // +buf*4096
  USH* lV = Vt + w * 512 + lane * 8;   // +buf*4096

  // issue tile 0 -> buf 0
  gld_lds16(gK0, lK);
  gld_lds16(gV0, lV);

  for (int kt = 0; kt < 64; ++kt) {
    const int buf = kt & 1;
    __syncthreads();  // implicit vmcnt(0): tile kt resident; buf^1 free
    if (kt < 63) {    // issue tile kt+1 -> buf^1; flies across this iteration
      const int nb = (buf ^ 1) * 4096;
      gld_lds16(gK0 + (size_t)(kt + 1) * 4096, lK + nb);
      gld_lds16(gV0 + (size_t)(kt + 1) * 64, lV + nb);
    }

    // S^T[key][qrow] = K * Q^T  (Q pre-scaled; st IS the exp2 argument)
    f32x4 st[4] = {};
    #pragma unroll
    for (int kh = 0; kh < 2; ++kh) {
      s16x8 ak[4];
      #pragma unroll
      for (int kff = 0; kff < 4; ++kff) {
        const int row = kff * 16 + c;
        const int qsw = (g ^ ((c >> 1) & 3)) * 8;
        ak[kff] = *(const s16x8_a*)(Ks + buf * 4096 + kh * 2048 + row * 32 + qsw);
      }
      #pragma unroll
      for (int kff = 0; kff < 4; ++kff)
        st[kff] = mfma16(ak[kff], qf[kh], st[kff]);
    }

    // p = exp2(s)
    #pragma unroll
    for (int kff = 0; kff < 4; ++kff)
      #pragma unroll
      for (int r = 0; r < 4; ++r)
        st[kff][r] = EXP2F(st[kff][r]);

    // write P to Ps[w][qrow][key] (wave-local; in-order DS, no barrier)
    #pragma unroll
    for (int kff = 0; kff < 4; ++kff) {
      const unsigned int lo = pk_bf16(st[kff][0], st[kff][1]);
      const unsigned int hi = pk_bf16(st[kff][2], st[kff][3]);
      *(u64_a*)(&Ps[w][c * 76 + kff * 16 + g * 4]) =
          (unsigned long long)lo | ((unsigned long long)hi << 32);
    }

    // O[qrow][hd] += P * V ; l[qrow] += P . 1
    #pragma unroll
    for (int kf = 0; kf < 2; ++kf) {
      const s16x8 ap = *(const s16x8_a*)(&Ps[w][c * 76 + kf * 32 + g * 8]);
      s16x8 bv[4];
      #pragma unroll
      for (int hf = 0; hf < 4; ++hf) {
        const int qv = ((kf * 4 + g) ^ (c & 7)) * 8;
        bv[hf] = *(const s16x8_a*)(Vt + buf * 4096 + (c + 16 * hf) * 64 + qv);
      }
      #pragma unroll
      for (int hf = 0; hf < 4; ++hf)
        o[hf] = mfma16(ap, bv[hf], o[hf]);
      o_l = mfma16(ap, onesf, o_l);
    }
  }

  // l lives in lanes c==0 (D[m][0]); broadcast within the wave via LDS
  if (c == 0) {
    #pragma unroll
    for (int r = 0; r < 4; ++r) lbuf[w][g * 4 + r] = o_l[r];
  }
  __syncthreads();

  #pragma unroll
  for (int r = 0; r < 4; ++r) {
    const int ml = g * 4 + r;
    const float linv = 1.0f / lbuf[w][ml];
    const int qrow = q0 + ml;
    #pragma unroll
    for (int hf = 0; hf < 4; ++hf) {
      const int hd = c + 16 * hf;
      att[((size_t)(bb * 4096 + qrow)) * 512 + hh * 64 + hd] =
          f2bf(o[hf][r] * linv);
    }
  }
}

extern "C" void kernel_launch(void* const* d_in, const int* in_sizes, int n_in,
                              void* d_out, int out_size, void* d_ws, size_t ws_size,
                              hipStream_t stream) {
  (void)in_sizes; (void)n_in; (void)out_size; (void)ws_size;
  const float* x  = (const float*)d_in[0];
  const float* Wq = (const float*)d_in[1];
  const float* bq = (const float*)d_in[2];
  const float* Wk = (const float*)d_in[3];
  const float* bk = (const float*)d_in[4];
  const float* Wv = (const float*)d_in[5];
  const float* bv = (const float*)d_in[6];
  const float* Wo = (const float*)d_in[7];
  const float* bo = (const float*)d_in[8];
  USH* ws  = (USH*)d_ws;
  USH* wT  = ws;                       // 4 * 262144 bf16 transposed weights (2 MB)
  USH* kv  = ws + 1048576;             // K [B,H,S,Hd] + V [B,H,Hd,S] bf16 (16 MB)
  USH* att = ws + 1048576 + 8388608;   // 4194304 : attn out [B,S,D] bf16 (8 MB)
  float* outF = (float*)d_out;         // fp32 output (16 MB)
  USH* qscratch = (USH*)d_out;         // Q bf16 (8 MB), dead before final GEMM
  USH* xb = (USH*)d_out + 4194304;     // x bf16 (8 MB), dead before final GEMM

  transpose_w<<<dim3(16, 16, 4), dim3(32, 8), 0, stream>>>(Wq, Wk, Wv, Wo, wT);
  cvt_x<<<2048, 256, 0, stream>>>(x, xb);
  gemm_bias<1><<<dim3(64, 4, 3), 256, 0, stream>>>(xb, wT, bq, bk, bv,
                                                   qscratch, kv, nullptr);
  attn<<<dim3(32, 16), 512, 0, stream>>>(qscratch, kv, att);
  gemm_bias<0><<<dim3(64, 4, 1), 256, 0, stream>>>(att, wT + 3 * 262144, bo, bo, bo,
                                                   nullptr, nullptr, outF);
}

// Round 15
// 208.348 us; speedup vs baseline: 1.2161x; 1.2161x over previous
//
#include <hip/hip_runtime.h>

typedef unsigned short USH;
typedef short s16x8 __attribute__((ext_vector_type(8)));
typedef float f32x4 __attribute__((ext_vector_type(4)));
typedef float f32x4v __attribute__((ext_vector_type(4)));
typedef unsigned int u32x4 __attribute__((ext_vector_type(4)));
// may_alias variants for ALL type-punned LDS/global accesses.
typedef s16x8 s16x8_a __attribute__((may_alias));
typedef f32x4v f32x4v_a __attribute__((may_alias));
typedef u32x4 u32x4_a __attribute__((may_alias));
typedef unsigned long long u64_a __attribute__((may_alias));

#if __has_builtin(__builtin_amdgcn_exp2f)
#define EXP2F(x) __builtin_amdgcn_exp2f(x)  // raw v_exp_f32, no legalization
#else
#define EXP2F(x) __builtin_exp2f(x)
#endif

__device__ __forceinline__ USH f2bf(float f) {
  union { float f; unsigned int i; } c; c.f = f;
  unsigned int x = c.i;
  return (USH)((x + 0x7FFFu + ((x >> 16) & 1u)) >> 16);
}
__device__ __forceinline__ unsigned int pk_bf16(float a, float b) {
#if __has_builtin(__builtin_amdgcn_cvt_pk_bf16_f32)
  typedef USH ush2 __attribute__((ext_vector_type(2)));
  union { ush2 v; unsigned int u; } r;
  r.v = __builtin_amdgcn_cvt_pk_bf16_f32(a, b);
  return r.u;
#else
  union { float f; unsigned int i; } ca, cb; ca.f = a; cb.f = b;
  return ((ca.i + 0x8000u) >> 16) | ((cb.i + 0x8000u) & 0xFFFF0000u);
#endif
}

__device__ __forceinline__ f32x4 mfma16(s16x8 a, s16x8 b, f32x4 c) {
  return __builtin_amdgcn_mfma_f32_16x16x32_bf16(a, b, c, 0, 0, 0);
}

// async global->LDS, 16B per lane; LDS dest semantics: wave base + lane*16.
#if __has_builtin(__builtin_amdgcn_global_load_lds)
__device__ __forceinline__ void gld_lds16(const USH* g, USH* l) {
  __builtin_amdgcn_global_load_lds(
      static_cast<const unsigned int __attribute__((address_space(1)))*>(
          (const void __attribute__((address_space(1)))*)g),
      static_cast<unsigned int __attribute__((address_space(3)))*>(
          (void __attribute__((address_space(3)))*)l),
      16, 0, 0);
}
#else
__device__ __forceinline__ void gld_lds16(const USH* g, USH* l) {
  *(s16x8_a*)l = *(const s16x8_a*)g;  // fallback: synchronous copy, same addresses
}
#endif

// ------------- prep: z<4 -> WT[n][k] = bf16(W[k][n]);  z==4 -> xb = bf16(x) -------------
__global__ __launch_bounds__(256) void prep(
    const float* __restrict__ Wq, const float* __restrict__ Wk,
    const float* __restrict__ Wv, const float* __restrict__ Wo,
    const float* __restrict__ x, USH* __restrict__ wsT, USH* __restrict__ xb) {
  __shared__ float tile[32][33];
  const int z = blockIdx.z;
  const int t = threadIdx.x;
  if (z == 4) {  // convert x: 256 blocks x 16384 floats
    const size_t b0 = ((size_t)blockIdx.y * 16 + blockIdx.x) * 16384;
    #pragma unroll
    for (int j = 0; j < 8; ++j) {
      const size_t i = b0 + (size_t)j * 2048 + t * 8;
      const f32x4v a = *(const f32x4v_a*)(x + i);
      const f32x4v b = *(const f32x4v_a*)(x + i + 4);
      u32x4 s;
      s.x = pk_bf16(a.x, a.y); s.y = pk_bf16(a.z, a.w);
      s.z = pk_bf16(b.x, b.y); s.w = pk_bf16(b.z, b.w);
      *(u32x4_a*)(xb + i) = s;
    }
    return;
  }
  const float* W = (z == 0) ? Wq : (z == 1) ? Wk : (z == 2) ? Wv : Wo;
  USH* WT = wsT + (size_t)z * 262144;
  const int n0 = blockIdx.x * 32, k0 = blockIdx.y * 32;
  const int tx = t & 31, ty = t >> 5;  // 32 x 8
  #pragma unroll
  for (int i = 0; i < 4; ++i)
    tile[ty + i * 8][tx] = W[(size_t)(k0 + ty + i * 8) * 512 + n0 + tx];
  __syncthreads();
  #pragma unroll
  for (int i = 0; i < 4; ++i)
    WT[(size_t)(n0 + ty + i * 8) * 512 + k0 + tx] = f2bf(tile[tx][ty + i * 8]);
}

// ---------------- GEMM: out = A[M,512](bf16) * WT^T + bias ----------------
// ROUND-13 PROVEN VERSION (round-14 operand-swap epilogue regressed −43us:
// per-lane b64/f32x4 stores put consecutive lanes 128B..2KB apart -> 16 cache
// lines per store inst vs 4 for the scalar-consecutive epilogue. Reverted.)
// MODE 0: float out[m*512+n] (d_out fp32).
// MODE 1: z==0 -> Q bf16 [B,H,S,Hd] scaled by sc*log2e; z==1 -> K [B,H,S,Hd];
//         z==2 -> V [B,H,Hd,S] (pre-transposed for attn).
// BK=64, register prefetch, 3 blocks/CU (768-block QKV dispatch single-pass).
template <int MODE>
__global__ __launch_bounds__(256, 3) void gemm_bias(
    const USH* __restrict__ A, const USH* __restrict__ BT0,
    const float* __restrict__ b0, const float* __restrict__ b1,
    const float* __restrict__ b2,
    USH* __restrict__ oQ, USH* __restrict__ oKV, float* __restrict__ oF) {
  __shared__ __align__(16) USH As[128 * 68];
  __shared__ __align__(16) USH Bs[128 * 68];
  const int z = blockIdx.z;
  const USH* BT = BT0 + (size_t)z * 262144;
  const float* bias = (z == 0) ? b0 : ((z == 1) ? b1 : b2);
  USH* outb = (z == 0) ? oQ : (oKV + (size_t)(z - 1) * 4194304);
  const float qs = (MODE == 1 && z == 0) ? 0.06375871528132839f : 1.0f;

  const int t = threadIdx.x;
  const int w = t >> 6, lane = t & 63;
  const int c = lane & 15, g = lane >> 4;
  const int wm = w & 1, wn = w >> 1;
  const int m0 = blockIdx.x * 128, n0 = blockIdx.y * 128;
  const int srow = t >> 1, scol = (t & 1) * 32;

  f32x4 acc[4][4] = {};

  const USH* Ap0 = A + (size_t)(m0 + srow) * 512 + scol;
  const USH* Bp0 = BT + (size_t)(n0 + srow) * 512 + scol;
  s16x8 pa[4], pb[4];
  #pragma unroll
  for (int j = 0; j < 4; ++j) {
    pa[j] = *(const s16x8_a*)(Ap0 + j * 8);
    pb[j] = *(const s16x8_a*)(Bp0 + j * 8);
  }

  for (int kt = 0; kt < 8; ++kt) {
    __syncthreads();
    #pragma unroll
    for (int j = 0; j < 4; ++j) {
      *(s16x8_a*)(As + srow * 68 + scol + j * 8) = pa[j];
      *(s16x8_a*)(Bs + srow * 68 + scol + j * 8) = pb[j];
    }
    const int ktn = (kt < 7) ? kt + 1 : kt;
    #pragma unroll
    for (int j = 0; j < 4; ++j) {
      pa[j] = *(const s16x8_a*)(Ap0 + ktn * 64 + j * 8);
      pb[j] = *(const s16x8_a*)(Bp0 + ktn * 64 + j * 8);
    }
    __syncthreads();
    #pragma unroll
    for (int ks = 0; ks < 2; ++ks) {
      s16x8 af[4], bfr[4];
      #pragma unroll
      for (int i = 0; i < 4; ++i) {
        af[i]  = *(const s16x8_a*)(As + (wm * 64 + i * 16 + c) * 68 + ks * 32 + g * 8);
        bfr[i] = *(const s16x8_a*)(Bs + (wn * 64 + i * 16 + c) * 68 + ks * 32 + g * 8);
      }
      #pragma unroll
      for (int mf = 0; mf < 4; ++mf)
        #pragma unroll
        for (int nf = 0; nf < 4; ++nf)
          acc[mf][nf] = mfma16(af[mf], bfr[nf], acc[mf][nf]);
    }
  }

  #pragma unroll
  for (int nf = 0; nf < 4; ++nf) {
    const int n = n0 + wn * 64 + nf * 16 + c;
    const float bv = bias[n];
    #pragma unroll
    for (int mf = 0; mf < 4; ++mf)
      #pragma unroll
      for (int r = 0; r < 4; ++r) {
        const int m = m0 + wm * 64 + mf * 16 + g * 4 + r;
        const float v = (acc[mf][nf][r] + bv) * qs;
        if (MODE == 0) {
          oF[(size_t)m * 512 + n] = v;
        } else {
          const int bb = m >> 12, s = m & 4095, h = n >> 6, hd = n & 63;
          if (z == 2)
            outb[(((size_t)(bb * 8 + h)) * 64 + hd) * 4096 + s] = f2bf(v);
          else
            outb[(((size_t)(bb * 8 + h)) * 4096 + s) * 64 + hd] = f2bf(v);
        }
      }
  }
}

// ---------------- flash attention v9: 8-wave blocks + async-DMA dbuf ----------------
// (round-14 proven: 102us, occupancy 40%, bank conflicts 0)
// grid: (32 q-tiles, 16 bh). block 512 = 8 waves, each wave owns 16 q-rows ->
// 16 waves/CU (2 blocks). K/V staged via global_load_lds into XOR-swizzled LDS:
//   K [half][key][64B]: phys chunk q holds global chunk q ^ ((key>>1)&3)
//   V [hd][128B]:       phys chunk q holds global chunk q ^ (hd&7)
// Double-buffered, one barrier/iter; DMA for kt+1 flies across the full iteration.
// Q pre-scaled by sc*log2e -> p = exp2(s). l = P.1 on the MFMA pipe.
__global__ __launch_bounds__(512, 4) void attn(const USH* __restrict__ Qbuf,
                                               const USH* __restrict__ kv,
                                               USH* __restrict__ att) {
  __shared__ __align__(16) USH Ks[2 * 4096];   // [buf][half*64+key][32 USH]
  __shared__ __align__(16) USH Vt[2 * 4096];   // [buf][64 hd][64 USH]
  __shared__ __align__(16) USH Ps[8][16 * 76]; // per-wave [16 qrow][76 key-pad]
  __shared__ float lbuf[8][16];

  const int t = threadIdx.x;
  const int w = t >> 6, lane = t & 63;
  const int c = lane & 15, g = lane >> 4;
  const int bh = blockIdx.y;
  const int bb = bh >> 3, hh = bh & 7;
  const size_t base = (size_t)bh * 262144;  // 4096*64
  const USH* Q = Qbuf + base;
  const USH* K = kv + base;                 // [S,Hd]
  const USH* V = kv + 4194304 + base;       // [Hd,S] (pre-transposed)
  const int q0 = blockIdx.x * 128 + w * 16;

  // Q fragments (B-operand of S^T): registers for the whole K loop
  s16x8 qf[2];
  #pragma unroll
  for (int kh = 0; kh < 2; ++kh)
    qf[kh] = *(const s16x8_a*)(Q + (size_t)(q0 + c) * 64 + kh * 32 + g * 8);

  // constant ones-column B-fragment: l = P . 1 on the MFMA pipe
  s16x8 onesf;
  {
    const short one = (short)0x3F80, val = (c == 0) ? one : (short)0;
    #pragma unroll
    for (int j = 0; j < 8; ++j) onesf[j] = val;
  }

  f32x4 o[4] = {};
  f32x4 o_l = {};

  // --- DMA lane mappings ---
  const int pK = w * 16 + (lane >> 2);
  const int keyK = pK & 63, halfK = pK >> 6;
  const int ccK = (lane & 3) ^ ((keyK >> 1) & 3);
  const USH* gK0 = K + (size_t)keyK * 64 + halfK * 32 + ccK * 8;  // +kt*4096
  const int hdV = w * 8 + (lane >> 3);
  const int ccV = (lane & 7) ^ (hdV & 7);
  const USH* gV0 = V + (size_t)hdV * 4096 + ccV * 8;              // +kt*64
  USH* lK = Ks + w * 512 + lane * 8;   // +buf*4096
  USH* lV = Vt + w * 512 + lane * 8;   // +buf*4096

  // issue tile 0 -> buf 0
  gld_lds16(gK0, lK);
  gld_lds16(gV0, lV);

  for (int kt = 0; kt < 64; ++kt) {
    const int buf = kt & 1;
    __syncthreads();  // implicit vmcnt(0): tile kt resident; buf^1 free
    if (kt < 63) {    // issue tile kt+1 -> buf^1; flies across this iteration
      const int nb = (buf ^ 1) * 4096;
      gld_lds16(gK0 + (size_t)(kt + 1) * 4096, lK + nb);
      gld_lds16(gV0 + (size_t)(kt + 1) * 64, lV + nb);
    }

    // S^T[key][qrow] = K * Q^T  (Q pre-scaled; st IS the exp2 argument)
    f32x4 st[4] = {};
    #pragma unroll
    for (int kh = 0; kh < 2; ++kh) {
      s16x8 ak[4];
      #pragma unroll
      for (int kff = 0; kff < 4; ++kff) {
        const int row = kff * 16 + c;
        const int qsw = (g ^ ((c >> 1) & 3)) * 8;
        ak[kff] = *(const s16x8_a*)(Ks + buf * 4096 + kh * 2048 + row * 32 + qsw);
      }
      #pragma unroll
      for (int kff = 0; kff < 4; ++kff)
        st[kff] = mfma16(ak[kff], qf[kh], st[kff]);
    }

    // p = exp2(s)
    #pragma unroll
    for (int kff = 0; kff < 4; ++kff)
      #pragma unroll
      for (int r = 0; r < 4; ++r)
        st[kff][r] = EXP2F(st[kff][r]);

    // write P to Ps[w][qrow][key] (wave-local; in-order DS, no barrier)
    #pragma unroll
    for (int kff = 0; kff < 4; ++kff) {
      const unsigned int lo = pk_bf16(st[kff][0], st[kff][1]);
      const unsigned int hi = pk_bf16(st[kff][2], st[kff][3]);
      *(u64_a*)(&Ps[w][c * 76 + kff * 16 + g * 4]) =
          (unsigned long long)lo | ((unsigned long long)hi << 32);
    }

    // O[qrow][hd] += P * V ; l[qrow] += P . 1
    #pragma unroll
    for (int kf = 0; kf < 2; ++kf) {
      const s16x8 ap = *(const s16x8_a*)(&Ps[w][c * 76 + kf * 32 + g * 8]);
      s16x8 bv[4];
      #pragma unroll
      for (int hf = 0; hf < 4; ++hf) {
        const int qv = ((kf * 4 + g) ^ (c & 7)) * 8;
        bv[hf] = *(const s16x8_a*)(Vt + buf * 4096 + (c + 16 * hf) * 64 + qv);
      }
      #pragma unroll
      for (int hf = 0; hf < 4; ++hf)
        o[hf] = mfma16(ap, bv[hf], o[hf]);
      o_l = mfma16(ap, onesf, o_l);
    }
  }

  // l lives in lanes c==0 (D[m][0]); broadcast within the wave via LDS
  if (c == 0) {
    #pragma unroll
    for (int r = 0; r < 4; ++r) lbuf[w][g * 4 + r] = o_l[r];
  }
  __syncthreads();

  #pragma unroll
  for (int r = 0; r < 4; ++r) {
    const int ml = g * 4 + r;
    const float linv = 1.0f / lbuf[w][ml];
    const int qrow = q0 + ml;
    #pragma unroll
    for (int hf = 0; hf < 4; ++hf) {
      const int hd = c + 16 * hf;
      att[((size_t)(bb * 4096 + qrow)) * 512 + hh * 64 + hd] =
          f2bf(o[hf][r] * linv);
    }
  }
}

extern "C" void kernel_launch(void* const* d_in, const int* in_sizes, int n_in,
                              void* d_out, int out_size, void* d_ws, size_t ws_size,
                              hipStream_t stream) {
  (void)in_sizes; (void)n_in; (void)out_size; (void)ws_size;
  const float* x  = (const float*)d_in[0];
  const float* Wq = (const float*)d_in[1];
  const float* bq = (const float*)d_in[2];
  const float* Wk = (const float*)d_in[3];
  const float* bk = (const float*)d_in[4];
  const float* Wv = (const float*)d_in[5];
  const float* bv = (const float*)d_in[6];
  const float* Wo = (const float*)d_in[7];
  const float* bo = (const float*)d_in[8];
  USH* ws  = (USH*)d_ws;
  USH* wT  = ws;                       // 4 * 262144 bf16 transposed weights (2 MB)
  USH* kv  = ws + 1048576;             // K [B,H,S,Hd] + V [B,H,Hd,S] bf16 (16 MB)
  USH* att = ws + 1048576 + 8388608;   // 4194304 : attn out [B,S,D] bf16 (8 MB)
  float* outF = (float*)d_out;         // fp32 output (16 MB)
  USH* qscratch = (USH*)d_out;         // Q bf16 (8 MB), dead before final GEMM
  USH* xb = (USH*)d_out + 4194304;     // x bf16 (8 MB), dead before final GEMM

  prep<<<dim3(16, 16, 5), 256, 0, stream>>>(Wq, Wk, Wv, Wo, x, wT, xb);
  gemm_bias<1><<<dim3(64, 4, 3), 256, 0, stream>>>(xb, wT, bq, bk, bv,
                                                   qscratch, kv, nullptr);
  attn<<<dim3(32, 16), 512, 0, stream>>>(qscratch, kv, att);
  gemm_bias<0><<<dim3(64, 4, 1), 256, 0, stream>>>(att, wT + 3 * 262144, bo, bo, bo,
                                                   nullptr, nullptr, outF);
}